// Round 2
// baseline (137.916 us; speedup 1.0000x reference)
//
#include <hip/hip_runtime.h>

// OESNN_SEPhIA_MultiTiled2: 32-step recurrent SNN, B=8192.
// R4: role-split fix for R3's redundancy regression. R3 (32 lanes/elem,
// 4 waves/SIMD) lifted VALUBusy 17->48% but every lane did BOTH the L0 dot
// and the L1 gather+dot (~110 issue slots/element vs R2's ~24) -> net slower.
// R4 keeps the 4 waves/SIMD but splits roles within each 32-lane group:
//   lanes 0..17  : layer-0 channel g only (x loads, 36-fma dot, LIF, pw)
//   lanes 18..25 : layer-1 output g-18 only (LDS-read pw, 36-fma dot, LIF)
// pw crosses lanes through a per-element LDS slot: 1 ds_write (L0 lanes) +
// 5 vector ds_reads (L1 lanes) instead of 18 ds_bpermutes -- same-wave DS is
// in-order so no barrier is needed, and each 32-lane group owns a private
// slot so there are no cross-wave races.
// Numerics are op-for-op identical to the R2/R3 passing kernels: p = x*1e-4
// (single rounding) feeding ascending-w single-accumulator fma chains,
// select-based LIF, pw values moved verbatim through LDS.

namespace {
constexpr int Tn = 32;
constexpr int Bn = 8192;
constexpr int O_PW = 0;                       // spks0 (= pw0) [T,B,18]
constexpr int O_S1 = Tn * Bn * 18;            // spks1 [T,B,8]
constexpr int O_M0 = O_S1 + Tn * Bn * 8;      // mems0 [T,B,18]
constexpr int O_M1 = O_M0 + Tn * Bn * 18;     // mems1 [T,B,8]
}

__global__ __launch_bounds__(256, 4)
void oesnn_kernel(const float* __restrict__ x_in,
                  const float* __restrict__ W0g,   // [2,18,18]
                  const float* __restrict__ d0g,   // [2,9]
                  const float* __restrict__ W1g,   // [1,18,16]
                  const float* __restrict__ d1g,   // [1,8]
                  const float* __restrict__ peakg, // [36]
                  float* __restrict__ out)
{
    const int tid = blockIdx.x * 256 + threadIdx.x;
    const int b   = tid >> 5;                 // batch element (32 lanes/elem)
    const int g   = tid & 31;                 // lane within batch group
    const int eb  = threadIdx.x >> 5;         // block-local element 0..7
    const bool isL0 = (g < 18);
    const bool isL1 = (g >= 18) && (g < 26);

    // pw broadcast buffer: one 18-float slot per element; stride 20 dwords so
    // each slot base is 80B (16B-aligned for ds_read_b128).
    __shared__ float pwsh[8][20];

    // ---------------- per-lane weight preload into registers ----------------
    // Shared arrays: L0 lanes hold W0 even/odd columns of channel g; L1 lanes
    // hold W1 even/odd columns of output g-18. Union footprint = 36 regs.
    float wA[18], wB[18];
    float dd = 0.f, pon = 0.f, poff = 0.f;
    int tl = 0;

    if (isL0) {
        tl = g / 9;
        const int jc = g % 9;
        dd = d0g[tl * 9 + jc];
        #pragma unroll
        for (int w = 0; w < 18; ++w) {
            const float2 p = *(const float2*)(W0g + ((tl * 18 + w) * 18 + 2 * jc));
            wA[w] = p.x;
            wB[w] = p.y;
        }
        // pw0 takes exactly two values per channel: precompute via the
        // reference's complex-division -> abs -> square path (verbatim).
        const int c = g;
        const float wl    = 1550.0f + 0.8f * (float)c;
        const float halfw = 0.5f * (wl * 1e3f / 15000.0f);
        const float amp   = sqrtf((exp10f(peakg[c] / 10.0f) / 1000.0f) * 1e6f);
        {   // spike = 0: lo = (0.1 + 0i)/(1 + 0i) * amp
            const float lr = 0.1f * amp;
            const float a  = sqrtf(lr * lr);
            poff = a * a;
        }
        {   // spike = 1: delta = -250 / (0.5*fwhm)
            const float delta = -250.0f / halfw;
            const float den = fmaf(delta, delta, 1.0f);
            const float qr  = fmaf(delta, delta, 0.1f) / den;     // (g + d^2)/den
            const float qi  = (delta - 0.1f * delta) / den;       // (d - g*d)/den
            const float lr = qr * amp, li = qi * amp;
            const float a  = sqrtf(fmaf(lr, lr, li * li));
            pon = a * a;
        }
    } else {
        const int o = (g < 26) ? (g - 18) : 7;   // clamp idle lanes 26..31
        dd = d1g[o];
        #pragma unroll
        for (int w = 0; w < 18; ++w) {
            const float2 p = *(const float2*)(W1g + w * 16 + 2 * o);  // 8B-aligned
            wA[w] = p.x;
            wB[w] = p.y;
        }
    }

    // ---------------- state & pointers ----------------
    float mem0 = 0.f;   // L0 lanes: channel membrane
    float mem1 = 0.f;   // L1 lanes: output membrane

    const float* xp = x_in + (size_t)b * 36 + tl * 18;   // tl=0 for non-L0 lanes
    float* opw = out + O_PW + (size_t)b * 18 + g;        // valid when isL0
    float* om0 = out + O_M0 + (size_t)b * 18 + g;
    const int o1 = isL1 ? (g - 18) : 0;
    float* os1 = out + O_S1 + (size_t)b * 8 + o1;        // valid when isL1
    float* om1 = out + O_M1 + (size_t)b * 8 + o1;

    // prefetch t=0 inputs (18 floats = 9x float2) -- L0 lanes only
    float2 xv[9];
    if (isL0) {
        #pragma unroll
        for (int k = 0; k < 9; ++k) xv[k] = *(const float2*)(xp + 2 * k);
    }

    #pragma unroll 1
    for (int t = 0; t < Tn; ++t) {
        // ================= layer-0 phase (lanes 0..17) =================
        if (isL0) {
            // p = x * 1e-4, rounded once (identical arithmetic to R2/R3)
            float p[18];
            #pragma unroll
            for (int k = 0; k < 9; ++k) {
                p[2 * k]     = xv[k].x * 1e-4f;
                p[2 * k + 1] = xv[k].y * 1e-4f;
            }
            // prefetch next timestep while this one computes
            xp += Bn * 36;
            if (t < Tn - 1) {
                #pragma unroll
                for (int k = 0; k < 9; ++k) xv[k] = *(const float2*)(xp + 2 * k);
            }
            // even/odd column dots: ascending w, single accumulator each
            float se = 0.f, so = 0.f;
            #pragma unroll
            for (int w = 0; w < 18; ++w) {
                se = fmaf(p[w], wA[w], se);
                so = fmaf(p[w], wB[w], so);
            }
            const float c0 = (se - so) * dd;
            const float m2 = (mem0 > 0.55f) ? 0.0f : fmaf(0.95f, mem0, c0);
            mem0 = m2;
            const float pw = (m2 > 0.55f) ? pon : poff;

            *opw = pw;            // 18 consecutive dwords per element
            *om0 = m2;
            pwsh[eb][g] = pw;     // broadcast to L1 lanes (same wave, in-order DS)
        }

        // ================= layer-1 phase (lanes 18..25) =================
        if (isL1) {
            // ds_read_b128 x4 + ds_read_b64: 8 lanes/element read the same
            // addresses -> LDS broadcast, no bank conflicts.
            const float4 qa = *(const float4*)&pwsh[eb][0];
            const float4 qb = *(const float4*)&pwsh[eb][4];
            const float4 qc = *(const float4*)&pwsh[eb][8];
            const float4 qd = *(const float4*)&pwsh[eb][12];
            const float2 qe = *(const float2*)&pwsh[eb][16];
            const float pwall[18] = {qa.x, qa.y, qa.z, qa.w,
                                     qb.x, qb.y, qb.z, qb.w,
                                     qc.x, qc.y, qc.z, qc.w,
                                     qd.x, qd.y, qd.z, qd.w,
                                     qe.x, qe.y};
            // ascending-c fma chains (identical order to the passing kernels)
            float i1e = 0.f, i1o = 0.f;
            #pragma unroll
            for (int c = 0; c < 18; ++c) {
                i1e = fmaf(pwall[c], wA[c], i1e);
                i1o = fmaf(pwall[c], wB[c], i1o);
            }
            const float c1 = (i1e - i1o) * dd;
            const float m3 = (mem1 > 0.25f) ? 0.0f : fmaf(0.95f, mem1, c1);
            mem1 = m3;
            *os1 = (m3 > 0.25f) ? 1.0f : 0.0f;   // 8 consecutive dwords per element
            *om1 = m3;
        }

        opw += Bn * 18;
        om0 += Bn * 18;
        os1 += Bn * 8;
        om1 += Bn * 8;
    }
}

extern "C" void kernel_launch(void* const* d_in, const int* in_sizes, int n_in,
                              void* d_out, int out_size, void* d_ws, size_t ws_size,
                              hipStream_t stream) {
    (void)in_sizes; (void)n_in; (void)out_size; (void)d_ws; (void)ws_size;
    const float* x  = (const float*)d_in[0];
    const float* W0 = (const float*)d_in[1];
    const float* d0 = (const float*)d_in[2];
    const float* W1 = (const float*)d_in[3];
    const float* d1 = (const float*)d_in[4];
    const float* pk = (const float*)d_in[5];
    float* out = (float*)d_out;

    dim3 grid(Bn * 32 / 256), block(256);   // 262144 threads = 4096 waves
    hipLaunchKernelGGL(oesnn_kernel, grid, block, 0, stream,
                       x, W0, d0, W1, d1, pk, out);
}

// Round 3
// 117.873 us; speedup vs baseline: 1.1700x; 1.1700x over previous
//
#include <hip/hip_runtime.h>

// OESNN_SEPhIA_MultiTiled2: 32-step recurrent SNN, B=8192.
// R5: latency attack on the verified R2 structure (8 lanes/elem, 1024 waves).
// Evidence across R2/R3/R4: wall/iter ~= exposed x-load latency (~2700 cyc)
// because prefetch depth was 1 and issue/iter (~550 cyc) << latency. More
// waves (R3/R4) did NOT fix it -- all waves stall together. Fix: depth-4
// rotating register prefetch (wall/iter -> max(issue, L/4)). To make room
// (R2's VGPR_Count=120 proved the compiler was demoting the 144 weight regs
// to per-iter reloads), weights move to a 3.7 KB LDS pair-table: float4 =
// (e[2k], o[2k], e[2k+1], o[2k+1]) per (chan, k), read with ds_read_b128
// (8 unique addrs/wave, 8-way broadcast, ~2-way conflicts = free).
// Numerics bit-identical to R2: same weight VALUES (rerouted via LDS), same
// p = x*1e-4 single rounding, same ascending-w single-accumulator fma chains,
// same select-based LIF, same shfl gather.

namespace {
constexpr int Tn = 32;
constexpr int Bn = 8192;
constexpr int O_PW = 0;                       // spks0 (= pw0) [T,B,18]
constexpr int O_S1 = Tn * Bn * 18;            // spks1 [T,B,8]
constexpr int O_M0 = O_S1 + Tn * Bn * 8;      // mems0 [T,B,18]
constexpr int O_M1 = O_M0 + Tn * Bn * 18;     // mems1 [T,B,8]
}

__global__ __launch_bounds__(256, 1)
void oesnn_kernel(const float* __restrict__ x_in,
                  const float* __restrict__ W0g,   // [2,18,18]
                  const float* __restrict__ d0g,   // [2,9]
                  const float* __restrict__ W1g,   // [1,18,16]
                  const float* __restrict__ d1g,   // [1,8]
                  const float* __restrict__ peakg, // [36]
                  float* __restrict__ out)
{
    const int lt  = threadIdx.x & 63;         // lane in wave
    const int tid = blockIdx.x * 256 + threadIdx.x;
    const int b   = tid >> 3;                 // batch element
    const int sub = tid & 7;                  // lane within batch group
    const int tl  = sub >> 2;                 // layer-0 tile (0/1)
    const int q   = sub & 3;                  // lane within tile
    const int j0  = (q == 0) ? 0 : (2 * q + 1);   // first in-tile channel
    const int nj  = (q == 0) ? 3 : 2;             // real channel count (pad to 3)

    // ---------------- weights -> LDS pair-table (one-time) ----------------
    // lw0[tl][jc][k] = (W0e[2k], W0o[2k], W0e[2k+1], W0o[2k+1]) for chan (tl,jc)
    // lw1[o][k]      = (W1e[2k], W1o[2k], W1e[2k+1], W1o[2k+1]) for output o
    __shared__ float4 lw0[2][9][9];
    __shared__ float4 lw1[8][9];
    if (threadIdx.x < 162) {
        const int tl_ = threadIdx.x / 81;
        const int r   = threadIdx.x % 81;
        const int jc_ = r / 9, k_ = r % 9;
        const float* base = W0g + ((size_t)(tl_ * 18 + 2 * k_) * 18) + 2 * jc_;
        lw0[tl_][jc_][k_] = make_float4(base[0], base[1], base[18], base[19]);
    } else if (threadIdx.x < 234) {
        const int i  = threadIdx.x - 162;
        const int o_ = i / 9, k_ = i % 9;
        const float* base = W1g + (size_t)(2 * k_) * 16 + 2 * o_;
        lw1[o_][k_] = make_float4(base[0], base[1], base[16], base[17]);
    }

    // ---------------- per-lane scalar constants ----------------
    float dd0[3], pon[3], poff[3];
    #pragma unroll
    for (int j = 0; j < 3; ++j) {
        const int jc = (j < nj) ? (j0 + j) : j0;   // clamped dup stays in-lane
        dd0[j] = d0g[tl * 9 + jc];
        // pw0 takes exactly two values per channel: precompute via the
        // reference's complex-division -> abs -> square path (verbatim R2).
        const int c = tl * 9 + jc;
        const float wl    = 1550.0f + 0.8f * (float)c;
        const float halfw = 0.5f * (wl * 1e3f / 15000.0f);
        const float amp   = sqrtf((exp10f(peakg[c] / 10.0f) / 1000.0f) * 1e6f);
        {   // spike = 0: lo = (0.1 + 0i)/(1 + 0i) * amp
            const float lr = 0.1f * amp;
            const float a  = sqrtf(lr * lr);
            poff[j] = a * a;
        }
        {   // spike = 1: delta = -250 / (0.5*fwhm)
            const float delta = -250.0f / halfw;
            const float den = fmaf(delta, delta, 1.0f);
            const float qr  = fmaf(delta, delta, 0.1f) / den;     // (g + d^2)/den
            const float qi  = (delta - 0.1f * delta) / den;       // (d - g*d)/den
            const float lr = qr * amp, li = qi * amp;
            const float a  = sqrtf(fmaf(lr, lr, li * li));
            pon[j] = a * a;
        }
    }
    const float dd1 = d1g[sub];

    __syncthreads();   // weights staged

    // ---------------- state & pointers ----------------
    float mem0[3] = {0.f, 0.f, 0.f};
    float mem1 = 0.f;

    const float* xb = x_in + (size_t)b * 36 + tl * 18;
    float* opw = out + O_PW + (size_t)b * 18 + tl * 9 + j0;
    float* om0 = out + O_M0 + (size_t)b * 18 + tl * 9 + j0;
    float* os1 = out + O_S1 + (size_t)b * 8 + sub;
    float* om1 = out + O_M1 + (size_t)b * 8 + sub;

    const int basel = lt & ~7;

    // ---------------- depth-4 rotating x prefetch ----------------
    float2 xv0[9], xv1[9], xv2[9], xv3[9];
    {
        const float2* s0 = (const float2*)(xb);
        const float2* s1 = (const float2*)(xb + (size_t)1 * Bn * 36);
        const float2* s2 = (const float2*)(xb + (size_t)2 * Bn * 36);
        const float2* s3 = (const float2*)(xb + (size_t)3 * Bn * 36);
        #pragma unroll
        for (int k = 0; k < 9; ++k) { xv0[k] = s0[k]; xv1[k] = s1[k]; }
        #pragma unroll
        for (int k = 0; k < 9; ++k) { xv2[k] = s2[k]; xv3[k] = s3[k]; }
    }

    // one timestep; consumes xv, refills it for tcur+4 (issued ~4 iters early)
    auto body = [&](float2 (&xv)[9], int tcur) {
        // p = x * 1e-4, rounded once (identical arithmetic to R2)
        float p[18];
        #pragma unroll
        for (int k = 0; k < 9; ++k) {
            p[2 * k]     = xv[k].x * 1e-4f;
            p[2 * k + 1] = xv[k].y * 1e-4f;
        }
        // refill this buffer for tcur+4 (deep prefetch)
        if (tcur + 4 < Tn) {
            const float2* s = (const float2*)(xb + (size_t)(tcur + 4) * Bn * 36);
            #pragma unroll
            for (int k = 0; k < 9; ++k) xv[k] = s[k];
        }

        // ---- layer 0: even/odd column dots from LDS pair-table ----
        float pwv[3];
        #pragma unroll
        for (int j = 0; j < 3; ++j) {
            const int jc = (j < nj) ? (j0 + j) : j0;
            float se = 0.f, so = 0.f;
            #pragma unroll
            for (int k = 0; k < 9; ++k) {
                const float4 wv = lw0[tl][jc][k];
                se = fmaf(p[2 * k],     wv.x, se);   // w = 2k   (ascending w,
                so = fmaf(p[2 * k],     wv.y, so);   //  single accumulator each
                se = fmaf(p[2 * k + 1], wv.z, se);   //  -- same order as R2)
                so = fmaf(p[2 * k + 1], wv.w, so);
            }
            const float c0 = (se - so) * dd0[j];
            const float m  = mem0[j];
            const float m2 = (m > 0.55f) ? 0.0f : fmaf(0.95f, m, c0);
            mem0[j] = m2;
            pwv[j]  = (m2 > 0.55f) ? pon[j] : poff[j];
        }

        // store pw0 / mem0 (guard the dup channel on 2-channel lanes)
        #pragma unroll
        for (int j = 0; j < 3; ++j) {
            if (j < nj) {
                opw[j] = pwv[j];
                om0[j] = mem0[j];
            }
        }

        // ---- cross-lane gather of all 18 pw values (verbatim R2) ----
        float pwall[18];
        #pragma unroll
        for (int c = 0; c < 18; ++c) {
            const int tlc = c / 9, jc2 = c % 9;
            const int qo  = (jc2 < 3) ? 0 : ((jc2 - 1) / 2);   // owner lane-in-tile
            const int st  = (qo == 0) ? 0 : (2 * qo + 1);
            const int r   = jc2 - st;                          // owner's reg index
            pwall[c] = __shfl(pwv[r], basel + tlc * 4 + qo, 64);
        }

        // ---- layer 1: ascending-c fma chains from LDS pair-table ----
        float i1e = 0.f, i1o = 0.f;
        #pragma unroll
        for (int k = 0; k < 9; ++k) {
            const float4 wv = lw1[sub][k];
            i1e = fmaf(pwall[2 * k],     wv.x, i1e);
            i1o = fmaf(pwall[2 * k],     wv.y, i1o);
            i1e = fmaf(pwall[2 * k + 1], wv.z, i1e);
            i1o = fmaf(pwall[2 * k + 1], wv.w, i1o);
        }

        const float c1 = (i1e - i1o) * dd1;
        const float m  = mem1;
        const float m2 = (m > 0.25f) ? 0.0f : fmaf(0.95f, m, c1);
        mem1 = m2;
        *os1 = (m2 > 0.25f) ? 1.0f : 0.0f;   // 64 lanes -> 64 consecutive dwords
        *om1 = m2;

        opw += Bn * 18;
        om0 += Bn * 18;
        os1 += Bn * 8;
        om1 += Bn * 8;
    };

    #pragma unroll 1
    for (int t = 0; t < Tn; t += 4) {
        body(xv0, t);
        body(xv1, t + 1);
        body(xv2, t + 2);
        body(xv3, t + 3);
    }
}

extern "C" void kernel_launch(void* const* d_in, const int* in_sizes, int n_in,
                              void* d_out, int out_size, void* d_ws, size_t ws_size,
                              hipStream_t stream) {
    (void)in_sizes; (void)n_in; (void)out_size; (void)d_ws; (void)ws_size;
    const float* x  = (const float*)d_in[0];
    const float* W0 = (const float*)d_in[1];
    const float* d0 = (const float*)d_in[2];
    const float* W1 = (const float*)d_in[3];
    const float* d1 = (const float*)d_in[4];
    const float* pk = (const float*)d_in[5];
    float* out = (float*)d_out;

    dim3 grid(Bn * 8 / 256), block(256);   // 65536 threads = 1024 waves
    hipLaunchKernelGGL(oesnn_kernel, grid, block, 0, stream,
                       x, W0, d0, W1, d1, pk, out);
}